// Round 7
// baseline (236.482 us; speedup 1.0000x reference)
//
#include <hip/hip_runtime.h>
#include <stdint.h>

// LJ 12-6 over a neighbor list — round 17: ABLATION round.
// History: R2 direct 131us. R10/R12 fused xy-filter 74us. R13/R15 splits:
// list-consumer kernels pin at ~53us with 5.0M vs 2.3M gathers (2.2x) =>
// gather count NOT the limiter there. R16 pk-atomic test VOID: WRITE_SIZE
// byte-identical (25598.6 vs 25598.2 KB) => no v2f32 atomic on gfx950,
// builtin legalized to 2 scalar ops. Two candidate walls remain entangled:
// (a) ~993k scattered device-scope atomic fadds, (b) divergent-gather
// latency + front-end. Fixed harness overhead ~110us (dur_us - kernel_sum,
// constant R10-R16); idx mostly L3-resident across replays (FETCH 65.7MB
// < 102MB idx).
// THIS ROUND: scoring path byte-identical to R16 (fused_st 71.6us) PLUS one
// ablation dispatch abl_noatomic (same kernel, atomics -> asm value sinks,
// writes nothing). Readout: top-5 rows by name if >=~67us, else
// T_abl = total - 190. Pre-committed: T_abl ~40-50 => atomics ~25-30us
// serial -> attack atomics next; T_abl ~65-72 => atomics free -> attack
// gather pipeline with inline-asm counted vmcnt next.

typedef int   v4i __attribute__((ext_vector_type(4)));
typedef float v4f __attribute__((ext_vector_type(4)));
typedef float v2f __attribute__((ext_vector_type(2)));

#define GRP    8
#define WGT    1024
#define NWG_F  256

// ---------------- packed f32x2 atomic add (legalized to 2 ops on gfx950) ----
#if __has_builtin(__builtin_amdgcn_global_atomic_fadd_v2f32)
__device__ __forceinline__ void pk_atomic_add(float* p, float a, float b) {
    typedef __attribute__((address_space(1))) v2f gv2f;
    v2f v; v.x = a; v.y = b;
    (void)__builtin_amdgcn_global_atomic_fadd_v2f32((gv2f*)(uintptr_t)p, v);
}
#else
__device__ __forceinline__ void pk_atomic_add(float* p, float a, float b) {
    atomicAdd(p, a);
    atomicAdd(p + 1, b);
}
#endif

// ---------------- prep: pad R to float4 AND build packed xy cell table ------
__global__ void __launch_bounds__(256) prep_kernel(
    const float* __restrict__ R, const float* __restrict__ cut_p,
    v4f* __restrict__ Rp, unsigned* __restrict__ packed, int n_atoms)
{
    int t = blockIdx.x * blockDim.x + threadIdx.x;
    int n_grp = (n_atoms + 4) / 5;
    if (t >= n_grp) return;
    const float inv_cut = 1.0f / cut_p[0];
    int a0 = t * 5;
    unsigned w = 0u;
#pragma unroll
    for (int k = 0; k < 5; ++k) {
        int a = a0 + k;
        if (a < n_atoms) {
            float x = R[3 * a + 0];
            float y = R[3 * a + 1];
            float z = R[3 * a + 2];
            v4f v; v.x = x; v.y = y; v.z = z; v.w = 0.0f;
            Rp[a] = v;  // 16B aligned: single-transaction gathers later
            int cx = min(7, max(0, (int)(x * inv_cut)));
            int cy = min(7, max(0, (int)(y * inv_cut)));
            w |= (unsigned)(cx | (cy << 3)) << (6 * k);
        }
        // padded atoms keep cell 0; (0,0) pairs rejected by r2>1e-10
    }
    packed[t] = w;
}

__global__ void __launch_bounds__(256) pad_R_kernel(
    const float* __restrict__ R, v4f* __restrict__ Rp, int n_atoms)
{
    int a = blockIdx.x * blockDim.x + threadIdx.x;
    if (a < n_atoms) {
        v4f v;
        v.x = R[3 * a + 0];
        v.y = R[3 * a + 1];
        v.z = R[3 * a + 2];
        v.w = 0.0f;
        Rp[a] = v;
    }
}

// one aligned ds_read_b32 per lookup: word = a/5 (magic mul), shift = (a%5)*6
__device__ __forceinline__ unsigned cell6w(const unsigned* __restrict__ lds32,
                                           unsigned a) {
    unsigned q = __umulhi(a, 0xCCCCCCCDu) >> 2;   // a / 5, exact for all u32
    unsigned r = a - q * 5u;                       // a % 5
    return (lds32[q] >> (r * 6u)) & 63u;
}

__device__ __forceinline__ void load_grp(
    const int* __restrict__ idx_i, const int* __restrict__ idx_j,
    int p, int n_pairs, int* __restrict__ is8, int* __restrict__ js8)
{
    if (p + GRP <= n_pairs) {   // p % 8 == 0 -> int4-aligned fast path
        v4i a0 = __builtin_nontemporal_load((const v4i*)idx_i + (p >> 2));
        v4i a1 = __builtin_nontemporal_load((const v4i*)idx_i + (p >> 2) + 1);
        v4i b0 = __builtin_nontemporal_load((const v4i*)idx_j + (p >> 2));
        v4i b1 = __builtin_nontemporal_load((const v4i*)idx_j + (p >> 2) + 1);
        is8[0] = a0.x; is8[1] = a0.y; is8[2] = a0.z; is8[3] = a0.w;
        is8[4] = a1.x; is8[5] = a1.y; is8[6] = a1.z; is8[7] = a1.w;
        js8[0] = b0.x; js8[1] = b0.y; js8[2] = b0.z; js8[3] = b0.w;
        js8[4] = b1.x; js8[5] = b1.y; js8[6] = b1.z; js8[7] = b1.w;
    } else {
#pragma unroll
        for (int k = 0; k < GRP; ++k) {
            bool v = (p + k < n_pairs);
            is8[k] = v ? idx_i[p + k] : 0;
            js8[k] = v ? idx_j[p + k] : 0;
        }
    }
}

// filter-and-select: failing pairs -> index 0 (broadcast gather of Rp[0];
// r2=0 -> rejected downstream). Constant VMEM issue count.
__device__ __forceinline__ void filt_sel(const unsigned* __restrict__ lds32,
                                         int* __restrict__ is8,
                                         int* __restrict__ js8)
{
#pragma unroll
    for (int k = 0; k < GRP; ++k) {
        unsigned ci = cell6w(lds32, (unsigned)is8[k]);
        unsigned cj = cell6w(lds32, (unsigned)js8[k]);
        int ddx = (int)(ci & 7u) - (int)(cj & 7u);
        int ddy = (int)(ci >> 3) - (int)(cj >> 3);
        bool ok = ((unsigned)(ddx + 1) <= 2u) & ((unsigned)(ddy + 1) <= 2u);
        is8[k] = ok ? is8[k] : 0;   // v_cndmask, no branch
        js8[k] = ok ? js8[k] : 0;
    }
}

// staged accumulation: st[atom] = (e, fx, fy, fz)
__device__ __forceinline__ void lj_body_st(
    v4f A, v4f B, float eps, float s2, float cut2, int gi,
    float* __restrict__ st)
{
    const float dx = A.x - B.x, dy = A.y - B.y, dz = A.z - B.z;
    const float r2 = dx * dx + dy * dy + dz * dz;
    if (r2 < cut2 && r2 > 1e-10f) {
        const float inv  = 1.0f / r2;
        const float sr2  = s2 * inv;
        const float sr6  = sr2 * sr2 * sr2;
        const float sr12 = sr6 * sr6;
        const float e    = 2.0f * eps * (sr12 - sr6);              // 0.5 * 4eps
        const float f    = 24.0f * eps * (2.0f * sr12 - sr6) * inv;
        float* p = st + ((size_t)(unsigned)gi << 2);
        pk_atomic_add(p,     e,      f * dx);
        pk_atomic_add(p + 2, f * dy, f * dz);
    }
}

// ablation body: identical math, atomics replaced by asm sinks (rule #17:
// keeps gathers/filter/LJ live without any memory traffic)
__device__ __forceinline__ void lj_body_sink(
    v4f A, v4f B, float eps, float s2, float cut2, int gi)
{
    const float dx = A.x - B.x, dy = A.y - B.y, dz = A.z - B.z;
    const float r2 = dx * dx + dy * dy + dz * dz;
    if (r2 < cut2 && r2 > 1e-10f) {
        const float inv  = 1.0f / r2;
        const float sr2  = s2 * inv;
        const float sr6  = sr2 * sr2 * sr2;
        const float sr12 = sr6 * sr6;
        const float e    = 2.0f * eps * (sr12 - sr6);
        const float f    = 24.0f * eps * (2.0f * sr12 - sr6) * inv;
        float fx = f * dx, fy = f * dy, fz = f * dz;
        int addr = gi << 2;                 // keep address calc comparable
        asm volatile("" :: "v"(e), "v"(fx), "v"(fy), "v"(fz), "v"(addr));
    }
}

// legacy direct-output accumulation (fallback paths)
__device__ __forceinline__ void lj_body(
    v4f A, v4f B, float eps, float s2, float cut2, int gi,
    float* __restrict__ energy, float* __restrict__ forces)
{
    const float dx = A.x - B.x, dy = A.y - B.y, dz = A.z - B.z;
    const float r2 = dx * dx + dy * dy + dz * dz;
    if (r2 < cut2 && r2 > 1e-10f) {
        const float inv  = 1.0f / r2;
        const float sr2  = s2 * inv;
        const float sr6  = sr2 * sr2 * sr2;
        const float sr12 = sr6 * sr6;
        const float e    = 2.0f * eps * (sr12 - sr6);
        const float f    = 24.0f * eps * (2.0f * sr12 - sr6) * inv;
        atomicAdd(&energy[gi], e);
        atomicAdd(&forces[3 * gi + 0], f * dx);
        atomicAdd(&forces[3 * gi + 1], f * dy);
        atomicAdd(&forces[3 * gi + 2], f * dz);
    }
}

// ---------------- scoring kernel (identical to R16) -------------------------
__global__ void __launch_bounds__(WGT, 4) lj_fused_st_kernel(
    const v4f* __restrict__ Rp,
    const unsigned* __restrict__ packed,
    const int* __restrict__ idx_i,
    const int* __restrict__ idx_j,
    const float* __restrict__ eps_p,
    const float* __restrict__ sig_p,
    const float* __restrict__ cut_p,
    float* __restrict__ st,
    int n_pairs, int pk_words, int chunk)
{
    extern __shared__ unsigned lds[];
    for (int w = threadIdx.x; w < pk_words; w += WGT)
        lds[w] = packed[w];
    __syncthreads();

    const float eps  = eps_p[0];
    const float sig  = sig_p[0];
    const float cut  = cut_p[0];
    const float s2   = sig * sig;
    const float cut2 = cut * cut;

    const int cs = blockIdx.x * chunk;
    const int ce = min(cs + chunk, n_pairs);
    const int STRIDE = WGT * GRP;

    int p0 = cs + (int)threadIdx.x * GRP;
    if (p0 >= ce) return;

    int isA[GRP], jsA[GRP], isB[GRP], jsB[GRP];

    load_grp(idx_i, idx_j, p0, n_pairs, isA, jsA);
    filt_sel(lds, isA, jsA);
    int p1 = p0 + STRIDE;

    while (true) {
        const bool h1 = p1 < ce;

        if (h1) load_grp(idx_i, idx_j, p1, n_pairs, isB, jsB);

        v4f Ri[GRP], Rj[GRP];
#pragma unroll
        for (int k = 0; k < GRP; ++k) { Ri[k] = Rp[isA[k]]; Rj[k] = Rp[jsA[k]]; }

        if (h1) filt_sel(lds, isB, jsB);

#pragma unroll
        for (int k = 0; k < GRP; ++k)
            lj_body_st(Ri[k], Rj[k], eps, s2, cut2, isA[k], st);

        if (!h1) break;
#pragma unroll
        for (int k = 0; k < GRP; ++k) { isA[k] = isB[k]; jsA[k] = jsB[k]; }
        p1 += STRIDE;
    }
}

// ---------------- ablation: same kernel, NO atomics -------------------------
__global__ void __launch_bounds__(WGT, 4) abl_noatomic_kernel(
    const v4f* __restrict__ Rp,
    const unsigned* __restrict__ packed,
    const int* __restrict__ idx_i,
    const int* __restrict__ idx_j,
    const float* __restrict__ eps_p,
    const float* __restrict__ sig_p,
    const float* __restrict__ cut_p,
    int n_pairs, int pk_words, int chunk)
{
    extern __shared__ unsigned lds[];
    for (int w = threadIdx.x; w < pk_words; w += WGT)
        lds[w] = packed[w];
    __syncthreads();

    const float eps  = eps_p[0];
    const float sig  = sig_p[0];
    const float cut  = cut_p[0];
    const float s2   = sig * sig;
    const float cut2 = cut * cut;

    const int cs = blockIdx.x * chunk;
    const int ce = min(cs + chunk, n_pairs);
    const int STRIDE = WGT * GRP;

    int p0 = cs + (int)threadIdx.x * GRP;
    if (p0 >= ce) return;

    int isA[GRP], jsA[GRP], isB[GRP], jsB[GRP];

    load_grp(idx_i, idx_j, p0, n_pairs, isA, jsA);
    filt_sel(lds, isA, jsA);
    int p1 = p0 + STRIDE;

    while (true) {
        const bool h1 = p1 < ce;

        if (h1) load_grp(idx_i, idx_j, p1, n_pairs, isB, jsB);

        v4f Ri[GRP], Rj[GRP];
#pragma unroll
        for (int k = 0; k < GRP; ++k) { Ri[k] = Rp[isA[k]]; Rj[k] = Rp[jsA[k]]; }

        if (h1) filt_sel(lds, isB, jsB);

#pragma unroll
        for (int k = 0; k < GRP; ++k)
            lj_body_sink(Ri[k], Rj[k], eps, s2, cut2, isA[k]);

        if (!h1) break;
#pragma unroll
        for (int k = 0; k < GRP; ++k) { isA[k] = isB[k]; jsA[k] = jsB[k]; }
        p1 += STRIDE;
    }
}

// staging -> output layout, pure stores (covers every element of d_out)
__global__ void __launch_bounds__(256) finalize_kernel(
    const v4f* __restrict__ st, float* __restrict__ energy,
    float* __restrict__ forces, int n_atoms)
{
    int a = blockIdx.x * blockDim.x + threadIdx.x;
    if (a < n_atoms) {
        v4f s = st[a];
        energy[a]          = s.x;
        forces[3 * a + 0]  = s.y;
        forces[3 * a + 1]  = s.z;
        forces[3 * a + 2]  = s.w;
    }
}

// ---------------- fallback A: direct-atomic fused ---------------------------
__global__ void __launch_bounds__(WGT, 4) lj_fused_kernel(
    const v4f* __restrict__ Rp,
    const unsigned* __restrict__ packed,
    const int* __restrict__ idx_i,
    const int* __restrict__ idx_j,
    const float* __restrict__ eps_p,
    const float* __restrict__ sig_p,
    const float* __restrict__ cut_p,
    float* __restrict__ energy,
    float* __restrict__ forces,
    int n_pairs, int pk_words, int chunk)
{
    extern __shared__ unsigned lds[];
    for (int w = threadIdx.x; w < pk_words; w += WGT)
        lds[w] = packed[w];
    __syncthreads();

    const float eps  = eps_p[0];
    const float sig  = sig_p[0];
    const float cut  = cut_p[0];
    const float s2   = sig * sig;
    const float cut2 = cut * cut;

    const int cs = blockIdx.x * chunk;
    const int ce = min(cs + chunk, n_pairs);
    const int STRIDE = WGT * GRP;

    int p0 = cs + (int)threadIdx.x * GRP;
    if (p0 >= ce) return;

    int isA[GRP], jsA[GRP], isB[GRP], jsB[GRP];
    load_grp(idx_i, idx_j, p0, n_pairs, isA, jsA);
    filt_sel(lds, isA, jsA);
    int p1 = p0 + STRIDE;

    while (true) {
        const bool h1 = p1 < ce;
        if (h1) load_grp(idx_i, idx_j, p1, n_pairs, isB, jsB);
        v4f Ri[GRP], Rj[GRP];
#pragma unroll
        for (int k = 0; k < GRP; ++k) { Ri[k] = Rp[isA[k]]; Rj[k] = Rp[jsA[k]]; }
        if (h1) filt_sel(lds, isB, jsB);
#pragma unroll
        for (int k = 0; k < GRP; ++k)
            lj_body(Ri[k], Rj[k], eps, s2, cut2, isA[k], energy, forces);
        if (!h1) break;
#pragma unroll
        for (int k = 0; k < GRP; ++k) { isA[k] = isB[k]; jsA[k] = jsB[k]; }
        p1 += STRIDE;
    }
}

// ---------------- fallback B: R2 structure ----------------------------------
#define PPT 8
__global__ void __launch_bounds__(256) lj_pairs_fb_kernel(
    const v4f* __restrict__ Rp,
    const v4i* __restrict__ idx_i4, const v4i* __restrict__ idx_j4,
    const float* __restrict__ eps_p, const float* __restrict__ sig_p,
    const float* __restrict__ cut_p,
    float* __restrict__ energy, float* __restrict__ forces, int n_oct)
{
    int t = blockIdx.x * blockDim.x + threadIdx.x;
    if (t >= n_oct) return;
    const float eps  = eps_p[0];
    const float sig  = sig_p[0];
    const float cut  = cut_p[0];
    const float s2   = sig * sig;
    const float cut2 = cut * cut;
    v4i ii0 = __builtin_nontemporal_load(idx_i4 + 2 * t);
    v4i ii1 = __builtin_nontemporal_load(idx_i4 + 2 * t + 1);
    v4i jj0 = __builtin_nontemporal_load(idx_j4 + 2 * t);
    v4i jj1 = __builtin_nontemporal_load(idx_j4 + 2 * t + 1);
    int is[PPT] = { ii0.x, ii0.y, ii0.z, ii0.w, ii1.x, ii1.y, ii1.z, ii1.w };
    int js[PPT] = { jj0.x, jj0.y, jj0.z, jj0.w, jj1.x, jj1.y, jj1.z, jj1.w };
    v4f Ri[PPT], Rj[PPT];
#pragma unroll
    for (int k = 0; k < PPT; ++k) Ri[k] = Rp[is[k]];
#pragma unroll
    for (int k = 0; k < PPT; ++k) Rj[k] = Rp[js[k]];
#pragma unroll
    for (int k = 0; k < PPT; ++k)
        lj_body(Ri[k], Rj[k], eps, s2, cut2, is[k], energy, forces);
}

__global__ void lj_pairs_fb_tail_kernel(
    const v4f* __restrict__ Rp,
    const int* __restrict__ idx_i, const int* __restrict__ idx_j,
    const float* __restrict__ eps_p, const float* __restrict__ sig_p,
    const float* __restrict__ cut_p,
    float* __restrict__ energy, float* __restrict__ forces,
    int start, int n_pairs)
{
    int p = start + blockIdx.x * blockDim.x + threadIdx.x;
    if (p >= n_pairs) return;
    const float eps = eps_p[0];
    const float sig = sig_p[0];
    const float cut = cut_p[0];
    lj_body(Rp[idx_i[p]], Rp[idx_j[p]], eps, sig * sig, cut * cut,
            idx_i[p], energy, forces);
}
// -----------------------------------------------------------------------------

extern "C" void kernel_launch(void* const* d_in, const int* in_sizes, int n_in,
                              void* d_out, int out_size, void* d_ws, size_t ws_size,
                              hipStream_t stream) {
    const float* R     = (const float*)d_in[0];
    const float* eps_p = (const float*)d_in[1];
    const float* sig_p = (const float*)d_in[2];
    const float* cut_p = (const float*)d_in[3];
    const int*   idx_i = (const int*)d_in[4];
    const int*   idx_j = (const int*)d_in[5];

    const int n_atoms = in_sizes[0] / 3;
    const int n_pairs = in_sizes[4];

    float* energy = (float*)d_out;
    float* forces = (float*)d_out + n_atoms;

    // ws layout: [Rp float4][packed cell table][staging float4]
    char* ws = (char*)d_ws;
    const size_t rp_b     = (((size_t)n_atoms * 16) + 255) & ~(size_t)255;
    const int    pk_words = (n_atoms + 4) / 5;
    const size_t pk_b     = (((size_t)pk_words * 4) + 255) & ~(size_t)255;
    const size_t st_b     = (((size_t)n_atoms * 16) + 255) & ~(size_t)255;
    const size_t lds_b    = (((size_t)pk_words * 4) + 15) & ~(size_t)15;

    const bool have_rp  = ws_size >= rp_b;
    const bool lds_ok   = lds_b <= 160000;
    const bool use_st   = have_rp && lds_ok
                          && (ws_size >= rp_b + pk_b + st_b);
    const bool use_old  = !use_st && have_rp && lds_ok
                          && (ws_size >= rp_b + pk_b);

    v4f*      Rp     = (v4f*)ws;
    unsigned* packed = (unsigned*)(ws + rp_b);
    float*    st     = (float*)(ws + rp_b + pk_b);

    if (use_st) {
        (void)hipMemsetAsync(st, 0, (size_t)n_atoms * 16, stream);

        int pblocks = (pk_words + 255) / 256;
        prep_kernel<<<pblocks, 256, 0, stream>>>(R, cut_p, Rp, packed, n_atoms);

        (void)hipFuncSetAttribute((const void*)lj_fused_st_kernel,
                                  hipFuncAttributeMaxDynamicSharedMemorySize,
                                  (int)lds_b);
        int chunk = (((n_pairs + NWG_F - 1) / NWG_F) + GRP - 1) & ~(GRP - 1);
        lj_fused_st_kernel<<<NWG_F, WGT, lds_b, stream>>>(
            Rp, packed, idx_i, idx_j, eps_p, sig_p, cut_p,
            st, n_pairs, pk_words, chunk);

        int fblocks = (n_atoms + 255) / 256;
        finalize_kernel<<<fblocks, 256, 0, stream>>>(
            (const v4f*)st, energy, forces, n_atoms);

        // ABLATION dispatch (writes nothing; after finalize so scoring path
        // is untouched; idx already L3-warm in steady-state replays)
        (void)hipFuncSetAttribute((const void*)abl_noatomic_kernel,
                                  hipFuncAttributeMaxDynamicSharedMemorySize,
                                  (int)lds_b);
        abl_noatomic_kernel<<<NWG_F, WGT, lds_b, stream>>>(
            Rp, packed, idx_i, idx_j, eps_p, sig_p, cut_p,
            n_pairs, pk_words, chunk);
    } else if (use_old) {
        (void)hipMemsetAsync(d_out, 0, (size_t)out_size * sizeof(float), stream);

        int pblocks = (pk_words + 255) / 256;
        prep_kernel<<<pblocks, 256, 0, stream>>>(R, cut_p, Rp, packed, n_atoms);

        (void)hipFuncSetAttribute((const void*)lj_fused_kernel,
                                  hipFuncAttributeMaxDynamicSharedMemorySize,
                                  (int)lds_b);
        int chunk = (((n_pairs + NWG_F - 1) / NWG_F) + GRP - 1) & ~(GRP - 1);
        lj_fused_kernel<<<NWG_F, WGT, lds_b, stream>>>(
            Rp, packed, idx_i, idx_j, eps_p, sig_p, cut_p,
            energy, forces, n_pairs, pk_words, chunk);
    } else if (have_rp) {
        (void)hipMemsetAsync(d_out, 0, (size_t)out_size * sizeof(float), stream);

        int blocks = (n_atoms + 255) / 256;
        pad_R_kernel<<<blocks, 256, 0, stream>>>(R, Rp, n_atoms);
        const int n_oct = n_pairs / PPT;
        const int start = n_oct * PPT;
        if (n_oct > 0) {
            int fblocks = (n_oct + 255) / 256;
            lj_pairs_fb_kernel<<<fblocks, 256, 0, stream>>>(
                Rp, (const v4i*)idx_i, (const v4i*)idx_j,
                eps_p, sig_p, cut_p, energy, forces, n_oct);
        }
        if (start < n_pairs) {
            lj_pairs_fb_tail_kernel<<<1, 64, 0, stream>>>(
                Rp, idx_i, idx_j, eps_p, sig_p, cut_p,
                energy, forces, start, n_pairs);
        }
    }
}

// Round 8
// 194.340 us; speedup vs baseline: 1.2168x; 1.2168x over previous
//
#include <hip/hip_runtime.h>
#include <stdint.h>

// LJ 12-6 over a neighbor list — round 18: wave-batched dense atomic flush.
// History: R2 direct 131us. R10/R12 fused xy-filter 74us (16 waves).
// R16 staging+pk-atomic: void (no v2f32 atomic on gfx950; WRITE_SIZE
// identical). R17 ABLATION: same kernel minus atomics = 45.5us vs 72 =>
// atomics cost 26.5us. Cause: true pairs are ~1.24 lanes/wave per k-step,
// so ~71% of k-steps issue 4 atomic instrs at 1-2 active lanes = ~568k
// sparse scattered atomic instructions (~29cy each of issue/drain).
// Also explains R13/R15: both list-consumers did ~1M scattered atomics ->
// both 53us regardless of gather count.
// THIS ROUND: per-wave LDS buffer (31 slots x {gi,e,fx,fy,fz}); passing
// lanes ballot-claim slots across the 8-pair group; one dense flush
// (lanes 0..nb-1, nb~10) issues the atomics => instr count 568k -> ~100k,
// lane-requests unchanged. Overflow (slot>=31) -> direct atomic (correct
// for any input). Table back to R10 16-atoms/3-words (150,004B) to fit
// buffers in the proven-safe 160,000B LDS bound. No barriers; buffers are
// wave-private; base is wave-uniform (ballot popcount).
// Pre-committed readout: ~52us => per-instruction model right; ~70us =>
// per-request L2 wall -> next round removes atomics via sort-by-i.

typedef int   v4i __attribute__((ext_vector_type(4)));
typedef float v4f __attribute__((ext_vector_type(4)));

#define GRP    8
#define WGT    1024
#define NWG_F  256
#define SLOTS  31     // per-wave buffer slots (20B each)

// ---------------- prep: pad R to float4 AND build packed xy cell table ------
// 16 atoms per 3 words (6 bits each: cx | cy<<3, cells of size cutoff,
// clamped 0..7). Clamp monotone -> conservative for ANY box/cutoff.
__global__ void __launch_bounds__(256) prep_kernel(
    const float* __restrict__ R, const float* __restrict__ cut_p,
    v4f* __restrict__ Rp, unsigned* __restrict__ packed, int n_atoms)
{
    int t = blockIdx.x * blockDim.x + threadIdx.x;
    int n_thr = (n_atoms + 15) >> 4;
    if (t == 0) packed[3 * n_thr] = 0u;   // read-pad word
    if (t >= n_thr) return;
    const float inv_cut = 1.0f / cut_p[0];
    int a0 = t << 4;
    unsigned w[3] = {0u, 0u, 0u};
#pragma unroll
    for (int k = 0; k < 16; ++k) {
        int a = a0 + k;
        unsigned c = 0u;
        if (a < n_atoms) {
            float x = R[3 * a + 0];
            float y = R[3 * a + 1];
            float z = R[3 * a + 2];
            v4f v; v.x = x; v.y = y; v.z = z; v.w = 0.0f;
            Rp[a] = v;  // 16B aligned: single-transaction gathers later
            int cx = min(7, max(0, (int)(x * inv_cut)));
            int cy = min(7, max(0, (int)(y * inv_cut)));
            c = (unsigned)(cx | (cy << 3));
        }
        int bit = 6 * k, word = bit >> 5, off = bit & 31;
        w[word] |= c << off;
        if (off > 26) w[word + 1] |= c >> (32 - off);
    }
    packed[3 * t + 0] = w[0];
    packed[3 * t + 1] = w[1];
    packed[3 * t + 2] = w[2];
}

__global__ void __launch_bounds__(256) pad_R_kernel(
    const float* __restrict__ R, v4f* __restrict__ Rp, int n_atoms)
{
    int a = blockIdx.x * blockDim.x + threadIdx.x;
    if (a < n_atoms) {
        v4f v;
        v.x = R[3 * a + 0];
        v.y = R[3 * a + 1];
        v.z = R[3 * a + 2];
        v.w = 0.0f;
        Rp[a] = v;
    }
}

// 6-bit cell lookup from byte-packed table (R10 layout)
__device__ __forceinline__ unsigned cell6(const unsigned char* c8, unsigned a) {
    unsigned bit = a * 6u;
    unsigned by  = bit >> 3;
    unsigned v   = (unsigned)c8[by] | ((unsigned)c8[by + 1] << 8);
    return (v >> (bit & 7u)) & 63u;
}

__device__ __forceinline__ void load_grp(
    const int* __restrict__ idx_i, const int* __restrict__ idx_j,
    int p, int n_pairs, int* __restrict__ is8, int* __restrict__ js8)
{
    if (p + GRP <= n_pairs) {   // p % 8 == 0 -> int4-aligned fast path
        v4i a0 = __builtin_nontemporal_load((const v4i*)idx_i + (p >> 2));
        v4i a1 = __builtin_nontemporal_load((const v4i*)idx_i + (p >> 2) + 1);
        v4i b0 = __builtin_nontemporal_load((const v4i*)idx_j + (p >> 2));
        v4i b1 = __builtin_nontemporal_load((const v4i*)idx_j + (p >> 2) + 1);
        is8[0] = a0.x; is8[1] = a0.y; is8[2] = a0.z; is8[3] = a0.w;
        is8[4] = a1.x; is8[5] = a1.y; is8[6] = a1.z; is8[7] = a1.w;
        js8[0] = b0.x; js8[1] = b0.y; js8[2] = b0.z; js8[3] = b0.w;
        js8[4] = b1.x; js8[5] = b1.y; js8[6] = b1.z; js8[7] = b1.w;
    } else {
#pragma unroll
        for (int k = 0; k < GRP; ++k) {
            bool v = (p + k < n_pairs);
            is8[k] = v ? idx_i[p + k] : 0;
            js8[k] = v ? idx_j[p + k] : 0;
        }
    }
}

__device__ __forceinline__ void load_or_zero(
    const int* __restrict__ idx_i, const int* __restrict__ idx_j,
    int p, int ce, int n_pairs, int* __restrict__ is8, int* __restrict__ js8)
{
    if (p < ce) {
        load_grp(idx_i, idx_j, p, n_pairs, is8, js8);
    } else {
#pragma unroll
        for (int k = 0; k < GRP; ++k) { is8[k] = 0; js8[k] = 0; }
    }
}

// filter-and-select: failing pairs -> index 0 (broadcast gather of Rp[0];
// r2=0 -> rejected downstream). Constant VMEM issue count.
__device__ __forceinline__ void filt_sel(const unsigned char* __restrict__ c8,
                                         int* __restrict__ is8,
                                         int* __restrict__ js8)
{
#pragma unroll
    for (int k = 0; k < GRP; ++k) {
        unsigned ci = cell6(c8, (unsigned)is8[k]);
        unsigned cj = cell6(c8, (unsigned)js8[k]);
        int ddx = (int)(ci & 7u) - (int)(cj & 7u);
        int ddy = (int)(ci >> 3) - (int)(cj >> 3);
        bool ok = ((unsigned)(ddx + 1) <= 2u) & ((unsigned)(ddy + 1) <= 2u);
        is8[k] = ok ? is8[k] : 0;   // v_cndmask, no branch
        js8[k] = ok ? js8[k] : 0;
    }
}

// legacy direct-output accumulation (fallback paths)
__device__ __forceinline__ void lj_body(
    v4f A, v4f B, float eps, float s2, float cut2, int gi,
    float* __restrict__ energy, float* __restrict__ forces)
{
    const float dx = A.x - B.x, dy = A.y - B.y, dz = A.z - B.z;
    const float r2 = dx * dx + dy * dy + dz * dz;
    if (r2 < cut2 && r2 > 1e-10f) {
        const float inv  = 1.0f / r2;
        const float sr2  = s2 * inv;
        const float sr6  = sr2 * sr2 * sr2;
        const float sr12 = sr6 * sr6;
        const float e    = 2.0f * eps * (sr12 - sr6);              // 0.5 * 4eps
        const float f    = 24.0f * eps * (2.0f * sr12 - sr6) * inv;
        atomicAdd(&energy[gi], e);
        atomicAdd(&forces[3 * gi + 0], f * dx);
        atomicAdd(&forces[3 * gi + 1], f * dy);
        atomicAdd(&forces[3 * gi + 2], f * dz);
    }
}

// ---------------- main kernel: fused + wave-batched atomic flush ------------
__global__ void __launch_bounds__(WGT, 4) lj_fused_st_kernel(
    const v4f* __restrict__ Rp,
    const unsigned* __restrict__ packed,
    const int* __restrict__ idx_i,
    const int* __restrict__ idx_j,
    const float* __restrict__ eps_p,
    const float* __restrict__ sig_p,
    const float* __restrict__ cut_p,
    float* __restrict__ st,
    int n_pairs, int pk_words, int chunk, int buf_off)
{
    extern __shared__ unsigned lds[];
    for (int w = threadIdx.x; w < pk_words; w += WGT)
        lds[w] = packed[w];
    __syncthreads();
    const unsigned char* c8 = (const unsigned char*)lds;
    unsigned* mybuf = lds + buf_off + (threadIdx.x >> 6) * (SLOTS * 5);
    const int lane = (int)(threadIdx.x & 63u);

    const float eps  = eps_p[0];
    const float sig  = sig_p[0];
    const float cut  = cut_p[0];
    const float s2   = sig * sig;
    const float cut2 = cut * cut;

    const int cs = blockIdx.x * chunk;
    const int ce = min(cs + chunk, n_pairs);
    const int S  = WGT * GRP;
    const int n_iter = (ce > cs) ? (ce - cs + S - 1) / S : 0;
    if (n_iter == 0) return;

    int isA[GRP], jsA[GRP], isB[GRP], jsB[GRP];
    int pA = cs + (int)threadIdx.x * GRP;

    load_or_zero(idx_i, idx_j, pA, ce, n_pairs, isA, jsA);
    filt_sel(c8, isA, jsA);

    for (int it = 0; it < n_iter; ++it) {
        const bool hB = (it + 1 < n_iter);
        const int  pB = pA + S;

        // (1) prefetch next group's indices
        if (hB) load_or_zero(idx_i, idx_j, pB, ce, n_pairs, isB, jsB);

        // (2) gathers — unconditional 32 x dwordx4 (filtered -> Rp[0] bcast)
        v4f Ri[GRP], Rj[GRP];
#pragma unroll
        for (int k = 0; k < GRP; ++k) { Ri[k] = Rp[isA[k]]; Rj[k] = Rp[jsA[k]]; }

        // (3) filter next group (gathers stay in flight)
        if (hB) filt_sel(c8, isB, jsB);

        // (4) compute + ballot-claim slots in the wave buffer
        unsigned base = 0u;
#pragma unroll
        for (int k = 0; k < GRP; ++k) {
            const v4f A = Ri[k], B = Rj[k];
            const float dx = A.x - B.x, dy = A.y - B.y, dz = A.z - B.z;
            const float r2 = dx * dx + dy * dy + dz * dz;
            const bool pass = (r2 < cut2) & (r2 > 1e-10f);
            const float inv  = 1.0f / r2;
            const float sr2  = s2 * inv;
            const float sr6  = sr2 * sr2 * sr2;
            const float sr12 = sr6 * sr6;
            const float e    = 2.0f * eps * (sr12 - sr6);          // 0.5*4eps
            const float f    = 24.0f * eps * (2.0f * sr12 - sr6) * inv;

            unsigned long long bal = __ballot(pass);
            if (pass) {
                int before = __builtin_amdgcn_mbcnt_hi(
                    (unsigned)(bal >> 32),
                    __builtin_amdgcn_mbcnt_lo((unsigned)bal, 0u));
                int slot = (int)base + before;
                if (slot < SLOTS) {
                    unsigned* b = mybuf + slot * 5;
                    b[0] = (unsigned)isA[k];
                    b[1] = __float_as_uint(e);
                    b[2] = __float_as_uint(f * dx);
                    b[3] = __float_as_uint(f * dy);
                    b[4] = __float_as_uint(f * dz);
                } else {
                    // overflow (rare): direct atomics — correctness never
                    // depends on buffer capacity
                    float* p = st + ((size_t)(unsigned)isA[k] << 2);
                    atomicAdd(p + 0, e);
                    atomicAdd(p + 1, f * dx);
                    atomicAdd(p + 2, f * dy);
                    atomicAdd(p + 3, f * dz);
                }
            }
            base += (unsigned)__popcll(bal);
            if (base > SLOTS) base = SLOTS;   // saturate: further claims direct
        }

        // (5) dense flush: lanes 0..nb-1 issue the atomics (nb<=31, ~10 avg)
        const int nb = (int)base;
        if (nb > 0 && lane < nb) {
            unsigned* b = mybuf + lane * 5;
            unsigned gi = b[0];
            float* p = st + ((size_t)gi << 2);
            atomicAdd(p + 0, __uint_as_float(b[1]));
            atomicAdd(p + 1, __uint_as_float(b[2]));
            atomicAdd(p + 2, __uint_as_float(b[3]));
            atomicAdd(p + 3, __uint_as_float(b[4]));
        }

        if (hB) {
#pragma unroll
            for (int k = 0; k < GRP; ++k) { isA[k] = isB[k]; jsA[k] = jsB[k]; }
            pA = pB;
        }
    }
}

// staging -> output layout, pure stores (covers every element of d_out)
__global__ void __launch_bounds__(256) finalize_kernel(
    const v4f* __restrict__ st, float* __restrict__ energy,
    float* __restrict__ forces, int n_atoms)
{
    int a = blockIdx.x * blockDim.x + threadIdx.x;
    if (a < n_atoms) {
        v4f s = st[a];
        energy[a]          = s.x;
        forces[3 * a + 0]  = s.y;
        forces[3 * a + 1]  = s.z;
        forces[3 * a + 2]  = s.w;
    }
}

// ---------------- fallback A: R12-style fused, direct atomics ---------------
__global__ void __launch_bounds__(WGT, 4) lj_fused_kernel(
    const v4f* __restrict__ Rp,
    const unsigned* __restrict__ packed,
    const int* __restrict__ idx_i,
    const int* __restrict__ idx_j,
    const float* __restrict__ eps_p,
    const float* __restrict__ sig_p,
    const float* __restrict__ cut_p,
    float* __restrict__ energy,
    float* __restrict__ forces,
    int n_pairs, int pk_words, int chunk)
{
    extern __shared__ unsigned lds[];
    for (int w = threadIdx.x; w < pk_words; w += WGT)
        lds[w] = packed[w];
    __syncthreads();
    const unsigned char* c8 = (const unsigned char*)lds;

    const float eps  = eps_p[0];
    const float sig  = sig_p[0];
    const float cut  = cut_p[0];
    const float s2   = sig * sig;
    const float cut2 = cut * cut;

    const int cs = blockIdx.x * chunk;
    const int ce = min(cs + chunk, n_pairs);
    const int S  = WGT * GRP;

    int p0 = cs + (int)threadIdx.x * GRP;
    if (p0 >= ce) return;

    int isA[GRP], jsA[GRP], isB[GRP], jsB[GRP];
    load_grp(idx_i, idx_j, p0, n_pairs, isA, jsA);
    filt_sel(c8, isA, jsA);
    int p1 = p0 + S;

    while (true) {
        const bool h1 = p1 < ce;
        if (h1) load_grp(idx_i, idx_j, p1, n_pairs, isB, jsB);
        v4f Ri[GRP], Rj[GRP];
#pragma unroll
        for (int k = 0; k < GRP; ++k) { Ri[k] = Rp[isA[k]]; Rj[k] = Rp[jsA[k]]; }
        if (h1) filt_sel(c8, isB, jsB);
#pragma unroll
        for (int k = 0; k < GRP; ++k)
            lj_body(Ri[k], Rj[k], eps, s2, cut2, isA[k], energy, forces);
        if (!h1) break;
#pragma unroll
        for (int k = 0; k < GRP; ++k) { isA[k] = isB[k]; jsA[k] = jsB[k]; }
        p1 += S;
    }
}

// ---------------- fallback B: R2 structure ----------------------------------
#define PPT 8
__global__ void __launch_bounds__(256) lj_pairs_fb_kernel(
    const v4f* __restrict__ Rp,
    const v4i* __restrict__ idx_i4, const v4i* __restrict__ idx_j4,
    const float* __restrict__ eps_p, const float* __restrict__ sig_p,
    const float* __restrict__ cut_p,
    float* __restrict__ energy, float* __restrict__ forces, int n_oct)
{
    int t = blockIdx.x * blockDim.x + threadIdx.x;
    if (t >= n_oct) return;
    const float eps  = eps_p[0];
    const float sig  = sig_p[0];
    const float cut  = cut_p[0];
    const float s2   = sig * sig;
    const float cut2 = cut * cut;
    v4i ii0 = __builtin_nontemporal_load(idx_i4 + 2 * t);
    v4i ii1 = __builtin_nontemporal_load(idx_i4 + 2 * t + 1);
    v4i jj0 = __builtin_nontemporal_load(idx_j4 + 2 * t);
    v4i jj1 = __builtin_nontemporal_load(idx_j4 + 2 * t + 1);
    int is[PPT] = { ii0.x, ii0.y, ii0.z, ii0.w, ii1.x, ii1.y, ii1.z, ii1.w };
    int js[PPT] = { jj0.x, jj0.y, jj0.z, jj0.w, jj1.x, jj1.y, jj1.z, jj1.w };
    v4f Ri[PPT], Rj[PPT];
#pragma unroll
    for (int k = 0; k < PPT; ++k) Ri[k] = Rp[is[k]];
#pragma unroll
    for (int k = 0; k < PPT; ++k) Rj[k] = Rp[js[k]];
#pragma unroll
    for (int k = 0; k < PPT; ++k)
        lj_body(Ri[k], Rj[k], eps, s2, cut2, is[k], energy, forces);
}

__global__ void lj_pairs_fb_tail_kernel(
    const v4f* __restrict__ Rp,
    const int* __restrict__ idx_i, const int* __restrict__ idx_j,
    const float* __restrict__ eps_p, const float* __restrict__ sig_p,
    const float* __restrict__ cut_p,
    float* __restrict__ energy, float* __restrict__ forces,
    int start, int n_pairs)
{
    int p = start + blockIdx.x * blockDim.x + threadIdx.x;
    if (p >= n_pairs) return;
    const float eps = eps_p[0];
    const float sig = sig_p[0];
    const float cut = cut_p[0];
    lj_body(Rp[idx_i[p]], Rp[idx_j[p]], eps, sig * sig, cut * cut,
            idx_i[p], energy, forces);
}
// -----------------------------------------------------------------------------

extern "C" void kernel_launch(void* const* d_in, const int* in_sizes, int n_in,
                              void* d_out, int out_size, void* d_ws, size_t ws_size,
                              hipStream_t stream) {
    const float* R     = (const float*)d_in[0];
    const float* eps_p = (const float*)d_in[1];
    const float* sig_p = (const float*)d_in[2];
    const float* cut_p = (const float*)d_in[3];
    const int*   idx_i = (const int*)d_in[4];
    const int*   idx_j = (const int*)d_in[5];

    const int n_atoms = in_sizes[0] / 3;
    const int n_pairs = in_sizes[4];

    float* energy = (float*)d_out;
    float* forces = (float*)d_out + n_atoms;

    // ws layout: [Rp float4][packed cell table][staging float4]
    char* ws = (char*)d_ws;
    const size_t rp_b     = (((size_t)n_atoms * 16) + 255) & ~(size_t)255;
    const int    n_thr16  = (n_atoms + 15) >> 4;
    const int    pk_words = 3 * n_thr16 + 1;             // +1 read-pad word
    const size_t pk_b     = (((size_t)pk_words * 4) + 255) & ~(size_t)255;
    const size_t st_b     = (((size_t)n_atoms * 16) + 255) & ~(size_t)255;

    const int    buf_off  = (pk_words + 3) & ~3;         // 16B-aligned words
    const size_t lds_b    = ((size_t)buf_off + 16u * SLOTS * 5u) * 4u;
    const size_t ldsF_b   = (((size_t)pk_words * 4) + 15) & ~(size_t)15;

    const bool have_rp  = ws_size >= rp_b;
    const bool lds_ok   = lds_b <= 160000;               // proven-safe bound
    const bool use_st   = have_rp && lds_ok
                          && (ws_size >= rp_b + pk_b + st_b);
    const bool use_old  = !use_st && have_rp && (ldsF_b <= 160000)
                          && (ws_size >= rp_b + pk_b);

    v4f*      Rp     = (v4f*)ws;
    unsigned* packed = (unsigned*)(ws + rp_b);
    float*    st     = (float*)(ws + rp_b + pk_b);

    if (use_st) {
        (void)hipMemsetAsync(st, 0, (size_t)n_atoms * 16, stream);

        int pblocks = (n_thr16 + 255) / 256;
        prep_kernel<<<pblocks, 256, 0, stream>>>(R, cut_p, Rp, packed, n_atoms);

        (void)hipFuncSetAttribute((const void*)lj_fused_st_kernel,
                                  hipFuncAttributeMaxDynamicSharedMemorySize,
                                  (int)lds_b);
        int chunk = (((n_pairs + NWG_F - 1) / NWG_F) + GRP - 1) & ~(GRP - 1);
        lj_fused_st_kernel<<<NWG_F, WGT, lds_b, stream>>>(
            Rp, packed, idx_i, idx_j, eps_p, sig_p, cut_p,
            st, n_pairs, pk_words, chunk, buf_off);

        int fblocks = (n_atoms + 255) / 256;
        finalize_kernel<<<fblocks, 256, 0, stream>>>(
            (const v4f*)st, energy, forces, n_atoms);
    } else if (use_old) {
        (void)hipMemsetAsync(d_out, 0, (size_t)out_size * sizeof(float), stream);

        int pblocks = (n_thr16 + 255) / 256;
        prep_kernel<<<pblocks, 256, 0, stream>>>(R, cut_p, Rp, packed, n_atoms);

        (void)hipFuncSetAttribute((const void*)lj_fused_kernel,
                                  hipFuncAttributeMaxDynamicSharedMemorySize,
                                  (int)ldsF_b);
        int chunk = (((n_pairs + NWG_F - 1) / NWG_F) + GRP - 1) & ~(GRP - 1);
        lj_fused_kernel<<<NWG_F, WGT, ldsF_b, stream>>>(
            Rp, packed, idx_i, idx_j, eps_p, sig_p, cut_p,
            energy, forces, n_pairs, pk_words, chunk);
    } else if (have_rp) {
        (void)hipMemsetAsync(d_out, 0, (size_t)out_size * sizeof(float), stream);

        int blocks = (n_atoms + 255) / 256;
        pad_R_kernel<<<blocks, 256, 0, stream>>>(R, Rp, n_atoms);
        const int n_oct = n_pairs / PPT;
        const int start = n_oct * PPT;
        if (n_oct > 0) {
            int fblocks = (n_oct + 255) / 256;
            lj_pairs_fb_kernel<<<fblocks, 256, 0, stream>>>(
                Rp, (const v4i*)idx_i, (const v4i*)idx_j,
                eps_p, sig_p, cut_p, energy, forces, n_oct);
        }
        if (start < n_pairs) {
            lj_pairs_fb_tail_kernel<<<1, 64, 0, stream>>>(
                Rp, idx_i, idx_j, eps_p, sig_p, cut_p,
                energy, forces, start, n_pairs);
        }
    }
}

// Round 9
// 187.932 us; speedup vs baseline: 1.2583x; 1.0341x over previous
//
#include <hip/hip_runtime.h>
#include <stdint.h>

// LJ 12-6 over a neighbor list — round 19: consolidation + L3 retention.
// History: R2 direct 131us (pure TA wall: 25.6M gather requests x 3.1cy).
// R10/R12 fused xy-filter 74us. R16 staging st[atom] (16B-contiguous
// accumulator -> 1 L2 line/pair vs d_out's 2) = 71.6us, session best
// structure. R17 ablation: atomics cost 26.5us of the fused kernel.
// R18 wave-batched dense flush: NULL (72.5) => atomic cost is per
// lane-REQUEST at TA/L2 (~16cy/req), not per instruction. 993k scattered
// f32 RMW requests are physics-fixed; fixed-point packing unsafe (near-
// coincident atoms -> ~1e15 values); no f64/pk f32 atomics help (R16).
// Fused TA budget: 60k cy gathers + 62k cy atomics ~= 51us floor; at 16
// waves/CU (150KB per-WG table, unshareable) overlap stops at ~72.
// THIS ROUND (low-risk bundle on the proven R16 structure):
//  (a) drop nontemporal hints on idx: working set (102MB idx + Rp + st +
//      out ~= 111MB) FITS the 256MB L3 across graph replays; NT forces
//      early eviction. FETCH_SIZE 65.7MB already shows partial caching.
//      Predicted FETCH_SIZE <= 55MB, fused 71.6 -> 68-70.
//  (b) zero the staging buffer inside prep (each thread zeroes its 5
//      atoms): -1 dispatch (no memset), -~2us.
// If FETCH_SIZE doesn't drop, the NT/L3 theory is wrong. Next decision
// point: inline-asm counted-vmcnt pipeline for the remaining 72->51 gap.

typedef int   v4i __attribute__((ext_vector_type(4)));
typedef float v4f __attribute__((ext_vector_type(4)));

#define GRP    8
#define WGT    1024
#define NWG_F  256

// ---------------- prep: Rp + packed xy cell table + zero staging ------------
// 5 atoms per 32-bit word, 6 bits each (cx | cy<<3, cells of size cutoff,
// clamped 0..7). Clamp monotone -> conservative for ANY box/cutoff.
__global__ void __launch_bounds__(256) prep_kernel(
    const float* __restrict__ R, const float* __restrict__ cut_p,
    v4f* __restrict__ Rp, unsigned* __restrict__ packed,
    v4f* __restrict__ st, int n_atoms)
{
    int t = blockIdx.x * blockDim.x + threadIdx.x;
    int n_grp = (n_atoms + 4) / 5;
    if (t >= n_grp) return;
    const float inv_cut = 1.0f / cut_p[0];
    int a0 = t * 5;
    unsigned w = 0u;
    const v4f zero = {0.0f, 0.0f, 0.0f, 0.0f};
#pragma unroll
    for (int k = 0; k < 5; ++k) {
        int a = a0 + k;
        if (a < n_atoms) {
            float x = R[3 * a + 0];
            float y = R[3 * a + 1];
            float z = R[3 * a + 2];
            v4f v; v.x = x; v.y = y; v.z = z; v.w = 0.0f;
            Rp[a] = v;   // 16B aligned: single-transaction gathers later
            st[a] = zero; // zero accumulator (replaces memset dispatch)
            int cx = min(7, max(0, (int)(x * inv_cut)));
            int cy = min(7, max(0, (int)(y * inv_cut)));
            w |= (unsigned)(cx | (cy << 3)) << (6 * k);
        }
        // padded atoms keep cell 0; (0,0) pairs rejected by r2>1e-10
    }
    packed[t] = w;
}

__global__ void __launch_bounds__(256) pad_R_kernel(
    const float* __restrict__ R, v4f* __restrict__ Rp, int n_atoms)
{
    int a = blockIdx.x * blockDim.x + threadIdx.x;
    if (a < n_atoms) {
        v4f v;
        v.x = R[3 * a + 0];
        v.y = R[3 * a + 1];
        v.z = R[3 * a + 2];
        v.w = 0.0f;
        Rp[a] = v;
    }
}

// one aligned ds_read_b32 per lookup: word = a/5 (magic mul), shift = (a%5)*6
__device__ __forceinline__ unsigned cell6w(const unsigned* __restrict__ lds32,
                                           unsigned a) {
    unsigned q = __umulhi(a, 0xCCCCCCCDu) >> 2;   // a / 5, exact for all u32
    unsigned r = a - q * 5u;                       // a % 5
    return (lds32[q] >> (r * 6u)) & 63u;
}

// plain (cacheable) vector loads — L3 keeps idx hot across graph replays
__device__ __forceinline__ void load_grp(
    const int* __restrict__ idx_i, const int* __restrict__ idx_j,
    int p, int n_pairs, int* __restrict__ is8, int* __restrict__ js8)
{
    if (p + GRP <= n_pairs) {   // p % 8 == 0 -> int4-aligned fast path
        v4i a0 = *((const v4i*)idx_i + (p >> 2));
        v4i a1 = *((const v4i*)idx_i + (p >> 2) + 1);
        v4i b0 = *((const v4i*)idx_j + (p >> 2));
        v4i b1 = *((const v4i*)idx_j + (p >> 2) + 1);
        is8[0] = a0.x; is8[1] = a0.y; is8[2] = a0.z; is8[3] = a0.w;
        is8[4] = a1.x; is8[5] = a1.y; is8[6] = a1.z; is8[7] = a1.w;
        js8[0] = b0.x; js8[1] = b0.y; js8[2] = b0.z; js8[3] = b0.w;
        js8[4] = b1.x; js8[5] = b1.y; js8[6] = b1.z; js8[7] = b1.w;
    } else {
#pragma unroll
        for (int k = 0; k < GRP; ++k) {
            bool v = (p + k < n_pairs);
            is8[k] = v ? idx_i[p + k] : 0;
            js8[k] = v ? idx_j[p + k] : 0;
        }
    }
}

// filter-and-select: failing pairs -> index 0 (broadcast gather of Rp[0];
// r2=0 -> rejected downstream). Constant VMEM issue count.
__device__ __forceinline__ void filt_sel(const unsigned* __restrict__ lds32,
                                         int* __restrict__ is8,
                                         int* __restrict__ js8)
{
#pragma unroll
    for (int k = 0; k < GRP; ++k) {
        unsigned ci = cell6w(lds32, (unsigned)is8[k]);
        unsigned cj = cell6w(lds32, (unsigned)js8[k]);
        int ddx = (int)(ci & 7u) - (int)(cj & 7u);
        int ddy = (int)(ci >> 3) - (int)(cj >> 3);
        bool ok = ((unsigned)(ddx + 1) <= 2u) & ((unsigned)(ddy + 1) <= 2u);
        is8[k] = ok ? is8[k] : 0;   // v_cndmask, no branch
        js8[k] = ok ? js8[k] : 0;
    }
}

// staged accumulation: st[atom] = (e, fx, fy, fz) — one 16B region per pair
__device__ __forceinline__ void lj_body_st(
    v4f A, v4f B, float eps, float s2, float cut2, int gi,
    float* __restrict__ st)
{
    const float dx = A.x - B.x, dy = A.y - B.y, dz = A.z - B.z;
    const float r2 = dx * dx + dy * dy + dz * dz;
    if (r2 < cut2 && r2 > 1e-10f) {
        const float inv  = 1.0f / r2;
        const float sr2  = s2 * inv;
        const float sr6  = sr2 * sr2 * sr2;
        const float sr12 = sr6 * sr6;
        const float e    = 2.0f * eps * (sr12 - sr6);              // 0.5 * 4eps
        const float f    = 24.0f * eps * (2.0f * sr12 - sr6) * inv;
        float* p = st + ((size_t)(unsigned)gi << 2);
        atomicAdd(p + 0, e);
        atomicAdd(p + 1, f * dx);
        atomicAdd(p + 2, f * dy);
        atomicAdd(p + 3, f * dz);
    }
}

// legacy direct-output accumulation (fallback paths)
__device__ __forceinline__ void lj_body(
    v4f A, v4f B, float eps, float s2, float cut2, int gi,
    float* __restrict__ energy, float* __restrict__ forces)
{
    const float dx = A.x - B.x, dy = A.y - B.y, dz = A.z - B.z;
    const float r2 = dx * dx + dy * dy + dz * dz;
    if (r2 < cut2 && r2 > 1e-10f) {
        const float inv  = 1.0f / r2;
        const float sr2  = s2 * inv;
        const float sr6  = sr2 * sr2 * sr2;
        const float sr12 = sr6 * sr6;
        const float e    = 2.0f * eps * (sr12 - sr6);
        const float f    = 24.0f * eps * (2.0f * sr12 - sr6) * inv;
        atomicAdd(&energy[gi], e);
        atomicAdd(&forces[3 * gi + 0], f * dx);
        atomicAdd(&forces[3 * gi + 1], f * dy);
        atomicAdd(&forces[3 * gi + 2], f * dz);
    }
}

// ---------------- main fused kernel (R16 structure) -------------------------
__global__ void __launch_bounds__(WGT, 4) lj_fused_st_kernel(
    const v4f* __restrict__ Rp,
    const unsigned* __restrict__ packed,
    const int* __restrict__ idx_i,
    const int* __restrict__ idx_j,
    const float* __restrict__ eps_p,
    const float* __restrict__ sig_p,
    const float* __restrict__ cut_p,
    float* __restrict__ st,
    int n_pairs, int pk_words, int chunk)
{
    extern __shared__ unsigned lds[];
    for (int w = threadIdx.x; w < pk_words; w += WGT)
        lds[w] = packed[w];
    __syncthreads();

    const float eps  = eps_p[0];
    const float sig  = sig_p[0];
    const float cut  = cut_p[0];
    const float s2   = sig * sig;
    const float cut2 = cut * cut;

    const int cs = blockIdx.x * chunk;
    const int ce = min(cs + chunk, n_pairs);
    const int STRIDE = WGT * GRP;

    int p0 = cs + (int)threadIdx.x * GRP;
    if (p0 >= ce) return;

    int isA[GRP], jsA[GRP], isB[GRP], jsB[GRP];

    load_grp(idx_i, idx_j, p0, n_pairs, isA, jsA);
    filt_sel(lds, isA, jsA);
    int p1 = p0 + STRIDE;

    while (true) {
        const bool h1 = p1 < ce;

        // (1) prefetch next group's indices
        if (h1) load_grp(idx_i, idx_j, p1, n_pairs, isB, jsB);

        // (2) gathers — unconditional 32 x dwordx4 (filtered -> Rp[0] bcast)
        v4f Ri[GRP], Rj[GRP];
#pragma unroll
        for (int k = 0; k < GRP; ++k) { Ri[k] = Rp[isA[k]]; Rj[k] = Rp[jsA[k]]; }

        // (3) filter next group (gathers stay in flight)
        if (h1) filt_sel(lds, isB, jsB);

        // (4) compute + sparse atomics into contiguous st[atom]
#pragma unroll
        for (int k = 0; k < GRP; ++k)
            lj_body_st(Ri[k], Rj[k], eps, s2, cut2, isA[k], st);

        if (!h1) break;
#pragma unroll
        for (int k = 0; k < GRP; ++k) { isA[k] = isB[k]; jsA[k] = jsB[k]; }
        p1 += STRIDE;
    }
}

// staging -> output layout, pure stores (covers every element of d_out)
__global__ void __launch_bounds__(256) finalize_kernel(
    const v4f* __restrict__ st, float* __restrict__ energy,
    float* __restrict__ forces, int n_atoms)
{
    int a = blockIdx.x * blockDim.x + threadIdx.x;
    if (a < n_atoms) {
        v4f s = st[a];
        energy[a]          = s.x;
        forces[3 * a + 0]  = s.y;
        forces[3 * a + 1]  = s.z;
        forces[3 * a + 2]  = s.w;
    }
}

// ---------------- fallback A: direct-atomic fused ---------------------------
__global__ void __launch_bounds__(WGT, 4) lj_fused_kernel(
    const v4f* __restrict__ Rp,
    const unsigned* __restrict__ packed,
    const int* __restrict__ idx_i,
    const int* __restrict__ idx_j,
    const float* __restrict__ eps_p,
    const float* __restrict__ sig_p,
    const float* __restrict__ cut_p,
    float* __restrict__ energy,
    float* __restrict__ forces,
    int n_pairs, int pk_words, int chunk)
{
    extern __shared__ unsigned lds[];
    for (int w = threadIdx.x; w < pk_words; w += WGT)
        lds[w] = packed[w];
    __syncthreads();

    const float eps  = eps_p[0];
    const float sig  = sig_p[0];
    const float cut  = cut_p[0];
    const float s2   = sig * sig;
    const float cut2 = cut * cut;

    const int cs = blockIdx.x * chunk;
    const int ce = min(cs + chunk, n_pairs);
    const int STRIDE = WGT * GRP;

    int p0 = cs + (int)threadIdx.x * GRP;
    if (p0 >= ce) return;

    int isA[GRP], jsA[GRP], isB[GRP], jsB[GRP];
    load_grp(idx_i, idx_j, p0, n_pairs, isA, jsA);
    filt_sel(lds, isA, jsA);
    int p1 = p0 + STRIDE;

    while (true) {
        const bool h1 = p1 < ce;
        if (h1) load_grp(idx_i, idx_j, p1, n_pairs, isB, jsB);
        v4f Ri[GRP], Rj[GRP];
#pragma unroll
        for (int k = 0; k < GRP; ++k) { Ri[k] = Rp[isA[k]]; Rj[k] = Rp[jsA[k]]; }
        if (h1) filt_sel(lds, isB, jsB);
#pragma unroll
        for (int k = 0; k < GRP; ++k)
            lj_body(Ri[k], Rj[k], eps, s2, cut2, isA[k], energy, forces);
        if (!h1) break;
#pragma unroll
        for (int k = 0; k < GRP; ++k) { isA[k] = isB[k]; jsA[k] = jsB[k]; }
        p1 += STRIDE;
    }
}

// ---------------- fallback B: R2 structure ----------------------------------
#define PPT 8
__global__ void __launch_bounds__(256) lj_pairs_fb_kernel(
    const v4f* __restrict__ Rp,
    const v4i* __restrict__ idx_i4, const v4i* __restrict__ idx_j4,
    const float* __restrict__ eps_p, const float* __restrict__ sig_p,
    const float* __restrict__ cut_p,
    float* __restrict__ energy, float* __restrict__ forces, int n_oct)
{
    int t = blockIdx.x * blockDim.x + threadIdx.x;
    if (t >= n_oct) return;
    const float eps  = eps_p[0];
    const float sig  = sig_p[0];
    const float cut  = cut_p[0];
    const float s2   = sig * sig;
    const float cut2 = cut * cut;
    v4i ii0 = *(idx_i4 + 2 * t);
    v4i ii1 = *(idx_i4 + 2 * t + 1);
    v4i jj0 = *(idx_j4 + 2 * t);
    v4i jj1 = *(idx_j4 + 2 * t + 1);
    int is[PPT] = { ii0.x, ii0.y, ii0.z, ii0.w, ii1.x, ii1.y, ii1.z, ii1.w };
    int js[PPT] = { jj0.x, jj0.y, jj0.z, jj0.w, jj1.x, jj1.y, jj1.z, jj1.w };
    v4f Ri[PPT], Rj[PPT];
#pragma unroll
    for (int k = 0; k < PPT; ++k) Ri[k] = Rp[is[k]];
#pragma unroll
    for (int k = 0; k < PPT; ++k) Rj[k] = Rp[js[k]];
#pragma unroll
    for (int k = 0; k < PPT; ++k)
        lj_body(Ri[k], Rj[k], eps, s2, cut2, is[k], energy, forces);
}

__global__ void lj_pairs_fb_tail_kernel(
    const v4f* __restrict__ Rp,
    const int* __restrict__ idx_i, const int* __restrict__ idx_j,
    const float* __restrict__ eps_p, const float* __restrict__ sig_p,
    const float* __restrict__ cut_p,
    float* __restrict__ energy, float* __restrict__ forces,
    int start, int n_pairs)
{
    int p = start + blockIdx.x * blockDim.x + threadIdx.x;
    if (p >= n_pairs) return;
    const float eps = eps_p[0];
    const float sig = sig_p[0];
    const float cut = cut_p[0];
    lj_body(Rp[idx_i[p]], Rp[idx_j[p]], eps, sig * sig, cut * cut,
            idx_i[p], energy, forces);
}
// -----------------------------------------------------------------------------

extern "C" void kernel_launch(void* const* d_in, const int* in_sizes, int n_in,
                              void* d_out, int out_size, void* d_ws, size_t ws_size,
                              hipStream_t stream) {
    const float* R     = (const float*)d_in[0];
    const float* eps_p = (const float*)d_in[1];
    const float* sig_p = (const float*)d_in[2];
    const float* cut_p = (const float*)d_in[3];
    const int*   idx_i = (const int*)d_in[4];
    const int*   idx_j = (const int*)d_in[5];

    const int n_atoms = in_sizes[0] / 3;
    const int n_pairs = in_sizes[4];

    float* energy = (float*)d_out;
    float* forces = (float*)d_out + n_atoms;

    // ws layout: [Rp float4][packed cell table][staging float4]
    char* ws = (char*)d_ws;
    const size_t rp_b     = (((size_t)n_atoms * 16) + 255) & ~(size_t)255;
    const int    pk_words = (n_atoms + 4) / 5;
    const size_t pk_b     = (((size_t)pk_words * 4) + 255) & ~(size_t)255;
    const size_t st_b     = (((size_t)n_atoms * 16) + 255) & ~(size_t)255;
    const size_t lds_b    = (((size_t)pk_words * 4) + 15) & ~(size_t)15;

    const bool have_rp  = ws_size >= rp_b;
    const bool lds_ok   = lds_b <= 160000;
    const bool use_st   = have_rp && lds_ok
                          && (ws_size >= rp_b + pk_b + st_b);
    const bool use_old  = !use_st && have_rp && lds_ok
                          && (ws_size >= rp_b + pk_b);

    v4f*      Rp     = (v4f*)ws;
    unsigned* packed = (unsigned*)(ws + rp_b);
    float*    st     = (float*)(ws + rp_b + pk_b);

    if (use_st) {
        // prep zeroes st in-kernel: no memset dispatch on the scoring path
        int pblocks = (pk_words + 255) / 256;
        prep_kernel<<<pblocks, 256, 0, stream>>>(
            R, cut_p, Rp, packed, (v4f*)st, n_atoms);

        (void)hipFuncSetAttribute((const void*)lj_fused_st_kernel,
                                  hipFuncAttributeMaxDynamicSharedMemorySize,
                                  (int)lds_b);
        int chunk = (((n_pairs + NWG_F - 1) / NWG_F) + GRP - 1) & ~(GRP - 1);
        lj_fused_st_kernel<<<NWG_F, WGT, lds_b, stream>>>(
            Rp, packed, idx_i, idx_j, eps_p, sig_p, cut_p,
            st, n_pairs, pk_words, chunk);

        int fblocks = (n_atoms + 255) / 256;
        finalize_kernel<<<fblocks, 256, 0, stream>>>(
            (const v4f*)st, energy, forces, n_atoms);
    } else if (use_old) {
        (void)hipMemsetAsync(d_out, 0, (size_t)out_size * sizeof(float), stream);

        int pblocks = (pk_words + 255) / 256;
        prep_kernel<<<pblocks, 256, 0, stream>>>(
            R, cut_p, Rp, packed, (v4f*)(ws + rp_b + pk_b), 0);  // st unused
        // NOTE: n_atoms=0 disables the loop; rebuild table via pad path:
        pad_R_kernel<<<(n_atoms + 255) / 256, 256, 0, stream>>>(R, Rp, n_atoms);

        (void)hipFuncSetAttribute((const void*)lj_fused_kernel,
                                  hipFuncAttributeMaxDynamicSharedMemorySize,
                                  (int)lds_b);
        int chunk = (((n_pairs + NWG_F - 1) / NWG_F) + GRP - 1) & ~(GRP - 1);
        lj_fused_kernel<<<NWG_F, WGT, lds_b, stream>>>(
            Rp, packed, idx_i, idx_j, eps_p, sig_p, cut_p,
            energy, forces, n_pairs, pk_words, chunk);
    } else if (have_rp) {
        (void)hipMemsetAsync(d_out, 0, (size_t)out_size * sizeof(float), stream);

        int blocks = (n_atoms + 255) / 256;
        pad_R_kernel<<<blocks, 256, 0, stream>>>(R, Rp, n_atoms);
        const int n_oct = n_pairs / PPT;
        const int start = n_oct * PPT;
        if (n_oct > 0) {
            int fblocks = (n_oct + 255) / 256;
            lj_pairs_fb_kernel<<<fblocks, 256, 0, stream>>>(
                Rp, (const v4i*)idx_i, (const v4i*)idx_j,
                eps_p, sig_p, cut_p, energy, forces, n_oct);
        }
        if (start < n_pairs) {
            lj_pairs_fb_tail_kernel<<<1, 64, 0, stream>>>(
                Rp, idx_i, idx_j, eps_p, sig_p, cut_p,
                energy, forces, start, n_pairs);
        }
    }
}